// Round 5
// baseline (791.430 us; speedup 1.0000x reference)
//
#include <hip/hip_runtime.h>
#include <hip/hip_bf16.h>
#include <cstdint>
#include <cmath>

// ---------------- types / helpers ----------------
typedef short short8 __attribute__((ext_vector_type(8)));
typedef float floatx4 __attribute__((ext_vector_type(4)));

#define EPSQ 1e-5f

__device__ __forceinline__ unsigned short f2bf(float f) {
  unsigned int u = __float_as_uint(f);
  return (unsigned short)((u + 0x7fffu + ((u >> 16) & 1u)) >> 16);
}
// async global->LDS, 16B per lane. LDS dest = wave-uniform base + lane*16.
__device__ __forceinline__ void async16(const void* g, void* l) {
  __builtin_amdgcn_global_load_lds(
      (const __attribute__((address_space(1))) unsigned int*)(uintptr_t)g,
      (__attribute__((address_space(3))) unsigned int*)(unsigned int)(uintptr_t)l,
      16, 0, 0);
}

// ---------------- init ----------------
__global__ void k_init(float* rowmax, double* sums) {
  int i = blockIdx.x * 256 + threadIdx.x;
  if (i < 16384) rowmax[i] = 0.0f;
  if (i < 2) sums[i] = 0.0;
}

// ---------------- abs-sum of 4194304 fp32 (-> fp64 acc) ----------------
__global__ __launch_bounds__(256) void k_absmean(const float* __restrict__ W,
                                                 double* __restrict__ acc) {
  __shared__ double wsum[4];
  const int tid = threadIdx.x;
  const size_t base = ((size_t)blockIdx.x * 256 + tid) * 8;
  float4 a = *(const float4*)(W + base);
  float4 b = *(const float4*)(W + base + 4);
  float s = fabsf(a.x) + fabsf(a.y) + fabsf(a.z) + fabsf(a.w) +
            fabsf(b.x) + fabsf(b.y) + fabsf(b.z) + fabsf(b.w);
  double d = (double)s;
#pragma unroll
  for (int i = 1; i < 64; i <<= 1) d += __shfl_xor(d, i);
  const int lane = tid & 63, wave = tid >> 6;
  if (lane == 0) wsum[wave] = d;
  __syncthreads();
  if (tid == 0) atomicAdd(acc, wsum[0] + wsum[1] + wsum[2] + wsum[3]);
}

// ---------------- ternary weight quant (fp32 in) -> integer-valued bf16 ----------------
__global__ __launch_bounds__(256) void k_quantw(const float* __restrict__ W,
                                                unsigned short* __restrict__ WQ,
                                                const double* __restrict__ sums) {
  const float s = fmaxf((float)(sums[0] * (1.0 / 4194304.0)), EPSQ);
  const float inv_s = 1.0f / s;
  const size_t base = ((size_t)blockIdx.x * 256 + threadIdx.x) * 8;
  float4 a = *(const float4*)(W + base);
  float4 b = *(const float4*)(W + base + 4);
  float v[8] = {a.x, a.y, a.z, a.w, b.x, b.y, b.z, b.w};
  unsigned int o[4];
#pragma unroll
  for (int j = 0; j < 4; ++j) {
    float ql = fminf(fmaxf(rintf(v[2 * j] * inv_s), -1.f), 1.f);
    float qh = fminf(fmaxf(rintf(v[2 * j + 1] * inv_s), -1.f), 1.f);
    o[j] = (unsigned int)f2bf(ql) | ((unsigned int)f2bf(qh) << 16);
  }
  int4 out;
  out.x = (int)o[0]; out.y = (int)o[1]; out.z = (int)o[2]; out.w = (int)o[3];
  *(int4*)(WQ + base) = out;
}

// ---------------- per-token int8 act quant of x (fp32 in, 1024/row) ----------------
__global__ __launch_bounds__(256) void k_quantx(const float* __restrict__ X,
                                                unsigned short* __restrict__ XQ,
                                                float* __restrict__ dqx) {
  __shared__ float wmax[4];
  const int row = blockIdx.x, tid = threadIdx.x;
  const size_t base = (size_t)row * 1024 + tid * 4;
  float4 a = *(const float4*)(X + base);
  float m = fmaxf(fmaxf(fabsf(a.x), fabsf(a.y)), fmaxf(fabsf(a.z), fabsf(a.w)));
#pragma unroll
  for (int i = 1; i < 64; i <<= 1) m = fmaxf(m, __shfl_xor(m, i));
  const int lane = tid & 63, wave = tid >> 6;
  if (lane == 0) wmax[wave] = m;
  __syncthreads();
  m = fmaxf(fmaxf(wmax[0], wmax[1]), fmaxf(wmax[2], wmax[3]));
  m = fmaxf(m, EPSQ);
  const float scale = 127.f / m;
  if (tid == 0) dqx[row] = m * (1.f / 127.f);
  unsigned int q0 = f2bf(fminf(fmaxf(rintf(a.x * scale), -128.f), 127.f));
  unsigned int q1 = f2bf(fminf(fmaxf(rintf(a.y * scale), -128.f), 127.f));
  unsigned int q2 = f2bf(fminf(fmaxf(rintf(a.z * scale), -128.f), 127.f));
  unsigned int q3 = f2bf(fminf(fmaxf(rintf(a.w * scale), -128.f), 127.f));
  int2 out;
  out.x = (int)(q0 | (q1 << 16));
  out.y = (int)(q2 | (q3 << 16));
  *(int2*)(XQ + base) = out;
}

// ---------------- shared GEMM mainloop: C[128x128] = A[128xK] * B[128xK]^T ----------
// A,B row-major bf16, leading dim KD. 4 waves (2x2), each 64x64 via 4x4 mfma 16x16x32.
// LDS tiles 128x64 bf16, XOR-swizzled 16B granules (physical granule g at row r
// holds logical granule g^(r&7)): global_load_lds stays lane-contiguous, ds_read_b128
// is 2-way (free). Equivalence with a padded-LDS reference mainloop verified R3/R4
// (bit-identical outputs).
template <int KD>
__device__ __forceinline__ void gemm_mainloop(const unsigned short* __restrict__ A,
                                              const unsigned short* __restrict__ B,
                                              int bm, int bn, int tid, char* lds,
                                              floatx4 (&acc)[4][4]) {
  const int wave = tid >> 6, lane = tid & 63;
  const int wm = wave >> 1, wn = wave & 1;
  const int kq = lane >> 4, lc = lane & 15;

  size_t ag[4], bg[4];
#pragma unroll
  for (int i = 0; i < 4; ++i) {
    int gidx = i * 256 + tid;
    int r = gidx >> 3, g = gidx & 7;
    int gs = g ^ (r & 7);
    ag[i] = (size_t)(bm * 128 + r) * KD + gs * 8;
    bg[i] = (size_t)(bn * 128 + r) * KD + gs * 8;
  }
  int aoff[2][4], boff[2][4];
#pragma unroll
  for (int ks = 0; ks < 2; ++ks) {
#pragma unroll
    for (int t = 0; t < 4; ++t) {
      int ra = wm * 64 + t * 16 + lc;
      aoff[ks][t] = ra * 128 + (((ks * 4 + kq) ^ (ra & 7)) << 4);
      int rb = wn * 64 + t * 16 + lc;
      boff[ks][t] = 16384 + rb * 128 + (((ks * 4 + kq) ^ (rb & 7)) << 4);
    }
  }
#pragma unroll
  for (int ti = 0; ti < 4; ++ti)
#pragma unroll
    for (int tj = 0; tj < 4; ++tj) {
      floatx4 z = {0.f, 0.f, 0.f, 0.f};
      acc[ti][tj] = z;
    }

  for (int kt = 0; kt < KD / 64; ++kt) {
    __syncthreads();
    const int k0 = kt * 64;
#pragma unroll
    for (int i = 0; i < 4; ++i) {
      async16(A + ag[i] + k0, lds + i * 4096 + wave * 1024);
      async16(B + bg[i] + k0, lds + 16384 + i * 4096 + wave * 1024);
    }
    asm volatile("s_waitcnt vmcnt(0)" ::: "memory");
    __syncthreads();
#pragma unroll
    for (int ks = 0; ks < 2; ++ks) {
      short8 af[4], bfr[4];
#pragma unroll
      for (int t = 0; t < 4; ++t) af[t] = *(const short8*)(lds + aoff[ks][t]);
#pragma unroll
      for (int t = 0; t < 4; ++t) bfr[t] = *(const short8*)(lds + boff[ks][t]);
#pragma unroll
      for (int ti = 0; ti < 4; ++ti)
#pragma unroll
        for (int tj = 0; tj < 4; ++tj)
          acc[ti][tj] =
              __builtin_amdgcn_mfma_f32_16x16x32_bf16(af[ti], bfr[tj], acc[ti][tj], 0, 0, 0);
    }
  }
}

// ---------------- GEMM1 + dequant + exact GELU + fp32 h store + row |h| max ---------
__global__ __launch_bounds__(256) void k_gemm1(const unsigned short* __restrict__ A,
                                               const unsigned short* __restrict__ B,
                                               const float* __restrict__ dqx,
                                               const double* __restrict__ sums,
                                               float* __restrict__ H,
                                               float* __restrict__ rowmax) {
  __shared__ __attribute__((aligned(16))) char lds[32768];
  __shared__ float smax[128];
  const int tid = threadIdx.x;
  const int bm = blockIdx.x, bn = blockIdx.y;
  if (tid < 128) smax[tid] = 0.0f;

  floatx4 acc[4][4];
  gemm_mainloop<1024>(A, B, bm, bn, tid, lds, acc);

  const int wave = tid >> 6, lane = tid & 63;
  const int wm = wave >> 1, wn = wave & 1;
  const int kq = lane >> 4, lc = lane & 15;
  const float s1 = fmaxf((float)(sums[0] * (1.0 / 4194304.0)), EPSQ);
#pragma unroll
  for (int ti = 0; ti < 4; ++ti) {
#pragma unroll
    for (int r = 0; r < 4; ++r) {
      const int lrow = wm * 64 + ti * 16 + kq * 4 + r;
      const int crow = bm * 128 + lrow;  // chunk-local row
      const float f = s1 * dqx[crow];
      float mx = 0.f;
#pragma unroll
      for (int tj = 0; tj < 4; ++tj) {
        const int gcol = bn * 128 + wn * 64 + tj * 16 + lc;
        float y = acc[ti][tj][r] * f;
        float h = 0.5f * y * (1.0f + erff(y * 0.70710678118654752f));
        H[(size_t)crow * 4096 + gcol] = h;
        mx = fmaxf(mx, fabsf(h));
      }
      atomicMax((unsigned int*)&smax[lrow], __float_as_uint(mx));
    }
  }
  __syncthreads();
  if (tid < 128)
    atomicMax((unsigned int*)&rowmax[bm * 128 + tid], __float_as_uint(smax[tid]));
}

// ---------------- per-row h scales (chunk of n rows) ----------------
__global__ void k_scaleh(const float* __restrict__ rowmax, float* __restrict__ qsh,
                         float* __restrict__ dqh, int n) {
  int i = blockIdx.x * 256 + threadIdx.x;
  if (i < n) {
    float m = fmaxf(rowmax[i], EPSQ);
    qsh[i] = 127.f / m;
    dqh[i] = m * (1.f / 127.f);
  }
}

// ---------------- quantize h (fp32, chunk-local) -> integer-valued bf16 ----------------
__global__ __launch_bounds__(256) void k_quanth(const float* __restrict__ H,
                                                const float* __restrict__ qsh,
                                                unsigned short* __restrict__ HQ) {
  const size_t gid = (size_t)blockIdx.x * 256 + threadIdx.x;
  const size_t base = gid * 4;
  const int row = (int)(base >> 12);  // 4096 per row
  const float q = qsh[row];
  float4 h = *(const float4*)(H + base);
  unsigned int q0 = f2bf(fminf(fmaxf(rintf(h.x * q), -128.f), 127.f));
  unsigned int q1 = f2bf(fminf(fmaxf(rintf(h.y * q), -128.f), 127.f));
  unsigned int q2 = f2bf(fminf(fmaxf(rintf(h.z * q), -128.f), 127.f));
  unsigned int q3 = f2bf(fminf(fmaxf(rintf(h.w * q), -128.f), 127.f));
  uint2 o;
  o.x = q0 | (q1 << 16);
  o.y = q2 | (q3 << 16);
  *(uint2*)(HQ + base) = o;
}

// ---------------- GEMM2 + dequant -> fp32 out (chunk-local) ----------------
__global__ __launch_bounds__(256) void k_gemm2(const unsigned short* __restrict__ A,
                                               const unsigned short* __restrict__ B,
                                               const float* __restrict__ dqh,
                                               const double* __restrict__ sums,
                                               float* __restrict__ OUT) {
  __shared__ __attribute__((aligned(16))) char lds[32768];
  const int tid = threadIdx.x;
  const int bm = blockIdx.x, bn = blockIdx.y;

  floatx4 acc[4][4];
  gemm_mainloop<4096>(A, B, bm, bn, tid, lds, acc);

  const int wave = tid >> 6, lane = tid & 63;
  const int wm = wave >> 1, wn = wave & 1;
  const int kq = lane >> 4, lc = lane & 15;
  const float s2 = fmaxf((float)(sums[0] * (1.0 / 4194304.0)), EPSQ);
#pragma unroll
  for (int ti = 0; ti < 4; ++ti) {
#pragma unroll
    for (int r = 0; r < 4; ++r) {
      const int crow = bm * 128 + wm * 64 + ti * 16 + kq * 4 + r;
      const float f = s2 * dqh[crow];
#pragma unroll
      for (int tj = 0; tj < 4; ++tj) {
        const int gcol = bn * 128 + wn * 64 + tj * 16 + lc;
        OUT[(size_t)crow * 1024 + gcol] = acc[ti][tj][r] * f;
      }
    }
  }
}

// ---------------- launcher ----------------
extern "C" void kernel_launch(void* const* d_in, const int* in_sizes, int n_in,
                              void* d_out, int out_size, void* d_ws, size_t ws_size,
                              hipStream_t stream) {
  const float* X  = (const float*)d_in[0];  // [16384][1024] fp32
  const float* W1 = (const float*)d_in[1];  // [4096][1024]  fp32
  const float* W2 = (const float*)d_in[2];  // [1024][4096]  fp32
  float* OUT = (float*)d_out;               // [16384][1024] fp32 (64 MB)

  char* ws = (char*)d_ws;
  // Fixed-footprint region: 17 MB
  unsigned short* W1Q = (unsigned short*)(ws);                       //  8 MB
  unsigned short* W2Q = (unsigned short*)(ws + (8u << 20));          //  8 MB
  float* DQX          = (float*)(ws + (16u << 20));                  // 64 KB
  float* ROWMAX       = (float*)(ws + (16u << 20) + 65536);          // 64 KB
  float* QSH          = (float*)(ws + (16u << 20) + 131072);         // 64 KB
  float* DQH          = (float*)(ws + (16u << 20) + 196608);         // 64 KB
  double* SUMS        = (double*)(ws + (16u << 20) + 262144);        // 16 B
  const size_t fixed  = 17u << 20;

  // XQ (16384x1024 bf16 = 32 MB) aliases the UPPER HALF of fp32 d_out (64 MB).
  // OUT writes through chunk c-1 cover bytes [0, c*R*4096); chunk c's gemm1 reads
  // XQ bytes 32MB + [c*R*2048, (c+1)*R*2048) — disjoint for all c (proof: overlap
  // needs c*R > 16384). Last chunk's gemm2 clobbers its own XQ tail only after
  // its gemm1 read (stream order). OUT writes re-cover all 64 MB (poison-safe).
  unsigned short* XQ = (unsigned short*)((char*)d_out + 33554432ull);

  // Pick largest row-chunk R fitting ws_size: need fixed + R*4096*(4+2) bytes.
  int R = 128;
  const int cands[6] = {4096, 2048, 1024, 512, 256, 128};
  for (int i = 0; i < 6; ++i) {
    if (fixed + (size_t)cands[i] * 24576ull <= ws_size) { R = cands[i]; break; }
  }
  unsigned short* HQ = (unsigned short*)(ws + fixed);                   // R*8192 B
  float* H           = (float*)(ws + fixed + (size_t)R * 8192ull);      // R*16384 B

  hipLaunchKernelGGL(k_init, dim3(64), dim3(256), 0, stream, ROWMAX, SUMS);
  hipLaunchKernelGGL(k_absmean, dim3(2048), dim3(256), 0, stream, W1, SUMS + 0);
  hipLaunchKernelGGL(k_absmean, dim3(2048), dim3(256), 0, stream, W2, SUMS + 1);
  hipLaunchKernelGGL(k_quantw, dim3(2048), dim3(256), 0, stream, W1, W1Q, SUMS + 0);
  hipLaunchKernelGGL(k_quantw, dim3(2048), dim3(256), 0, stream, W2, W2Q, SUMS + 1);
  hipLaunchKernelGGL(k_quantx, dim3(16384), dim3(256), 0, stream, X, XQ, DQX);

  const int nchunk = 16384 / R;
  for (int c = 0; c < nchunk; ++c) {
    const int row0 = c * R;
    hipLaunchKernelGGL(k_gemm1, dim3(R / 128, 32), dim3(256), 0, stream,
                       XQ + (size_t)row0 * 1024, W1Q, DQX + row0, SUMS, H, ROWMAX + row0);
    hipLaunchKernelGGL(k_scaleh, dim3((R + 255) / 256), dim3(256), 0, stream,
                       ROWMAX + row0, QSH + row0, DQH + row0, R);
    hipLaunchKernelGGL(k_quanth, dim3(R * 4), dim3(256), 0, stream, H, QSH + row0, HQ);
    hipLaunchKernelGGL(k_gemm2, dim3(R / 128, 8), dim3(256), 0, stream,
                       HQ, W2Q, DQH + row0, SUMS + 1, OUT + (size_t)row0 * 1024);
  }
}

// Round 6
// 445.728 us; speedup vs baseline: 1.7756x; 1.7756x over previous
//
#include <hip/hip_runtime.h>
#include <hip/hip_bf16.h>
#include <cstdint>
#include <cmath>

// ---------------- types / helpers ----------------
typedef int intx4 __attribute__((ext_vector_type(4)));

#define EPSQ 1e-5f

// async global->LDS, 16B per lane. LDS dest = wave-uniform base + lane*16.
__device__ __forceinline__ void async16(const void* g, void* l) {
  __builtin_amdgcn_global_load_lds(
      (const __attribute__((address_space(1))) unsigned int*)(uintptr_t)g,
      (__attribute__((address_space(3))) unsigned int*)(unsigned int)(uintptr_t)l,
      16, 0, 0);
}

__device__ __forceinline__ int q8(float v, float scale, float lo, float hi) {
  return (int)fminf(fmaxf(rintf(v * scale), lo), hi);
}

// ---------------- init ----------------
__global__ void k_init(float* rowmax, double* sums) {
  int i = blockIdx.x * 256 + threadIdx.x;
  if (i < 16384) rowmax[i] = 0.0f;
  if (i < 2) sums[i] = 0.0;
}

// ---------------- abs-sum of 4194304 fp32 (-> fp64 acc) ----------------
__global__ __launch_bounds__(256) void k_absmean(const float* __restrict__ W,
                                                 double* __restrict__ acc) {
  __shared__ double wsum[4];
  const int tid = threadIdx.x;
  const size_t base = ((size_t)blockIdx.x * 256 + tid) * 8;
  float4 a = *(const float4*)(W + base);
  float4 b = *(const float4*)(W + base + 4);
  float s = fabsf(a.x) + fabsf(a.y) + fabsf(a.z) + fabsf(a.w) +
            fabsf(b.x) + fabsf(b.y) + fabsf(b.z) + fabsf(b.w);
  double d = (double)s;
#pragma unroll
  for (int i = 1; i < 64; i <<= 1) d += __shfl_xor(d, i);
  const int lane = tid & 63, wave = tid >> 6;
  if (lane == 0) wsum[wave] = d;
  __syncthreads();
  if (tid == 0) atomicAdd(acc, wsum[0] + wsum[1] + wsum[2] + wsum[3]);
}

// ---------------- ternary weight quant (fp32 in) -> int8 {-1,0,1} ----------------
__global__ __launch_bounds__(256) void k_quantw(const float* __restrict__ W,
                                                signed char* __restrict__ WQ,
                                                const double* __restrict__ sums) {
  const float s = fmaxf((float)(sums[0] * (1.0 / 4194304.0)), EPSQ);
  const float inv_s = 1.0f / s;
  const size_t base = ((size_t)blockIdx.x * 256 + threadIdx.x) * 8;
  float4 a = *(const float4*)(W + base);
  float4 b = *(const float4*)(W + base + 4);
  float v[8] = {a.x, a.y, a.z, a.w, b.x, b.y, b.z, b.w};
  unsigned int lo = 0, hi = 0;
#pragma unroll
  for (int j = 0; j < 4; ++j) {
    lo |= ((unsigned int)(q8(v[j], inv_s, -1.f, 1.f) & 0xff)) << (8 * j);
    hi |= ((unsigned int)(q8(v[4 + j], inv_s, -1.f, 1.f) & 0xff)) << (8 * j);
  }
  uint2 o; o.x = lo; o.y = hi;
  *(uint2*)(WQ + base) = o;
}

// ---------------- per-token int8 act quant of x (fp32 in, 1024/row) ----------------
__global__ __launch_bounds__(256) void k_quantx(const float* __restrict__ X,
                                                signed char* __restrict__ XQ,
                                                float* __restrict__ dqx) {
  __shared__ float wmax[4];
  const int row = blockIdx.x, tid = threadIdx.x;
  const size_t base = (size_t)row * 1024 + tid * 4;
  float4 a = *(const float4*)(X + base);
  float m = fmaxf(fmaxf(fabsf(a.x), fabsf(a.y)), fmaxf(fabsf(a.z), fabsf(a.w)));
#pragma unroll
  for (int i = 1; i < 64; i <<= 1) m = fmaxf(m, __shfl_xor(m, i));
  const int lane = tid & 63, wave = tid >> 6;
  if (lane == 0) wmax[wave] = m;
  __syncthreads();
  m = fmaxf(fmaxf(wmax[0], wmax[1]), fmaxf(wmax[2], wmax[3]));
  m = fmaxf(m, EPSQ);
  const float scale = 127.f / m;
  if (tid == 0) dqx[row] = m * (1.f / 127.f);
  unsigned int p = ((unsigned int)(q8(a.x, scale, -128.f, 127.f) & 0xff)) |
                   ((unsigned int)(q8(a.y, scale, -128.f, 127.f) & 0xff) << 8) |
                   ((unsigned int)(q8(a.z, scale, -128.f, 127.f) & 0xff) << 16) |
                   ((unsigned int)(q8(a.w, scale, -128.f, 127.f) & 0xff) << 24);
  *(unsigned int*)(XQ + base) = p;
}

// ---------------- shared GEMM mainloop: C[128x128] = A[128xK] * B[128xK]^T ----------
// int8 operands, int32 exact accumulation via mfma_i32_16x16x64_i8.
// A,B row-major i8, row length KB bytes. 4 waves (2x2), each 64x64 via 4x4 MFMA.
// LDS tiles 128x128 i8 (16 KB each), XOR-swizzled 16B granules (physical granule g
// at row r holds logical granule g^(r&7)) — byte-identical addressing to the
// R5-verified bf16 mainloop; only element width and MFMA opcode change.
template <int KB>
__device__ __forceinline__ void gemm_mainloop(const signed char* __restrict__ A,
                                              const signed char* __restrict__ B,
                                              int bm, int bn, int tid, char* lds,
                                              intx4 (&acc)[4][4]) {
  const int wave = tid >> 6, lane = tid & 63;
  const int wm = wave >> 1, wn = wave & 1;
  const int kq = lane >> 4, lc = lane & 15;

  size_t ag[4], bg[4];
#pragma unroll
  for (int i = 0; i < 4; ++i) {
    int gidx = i * 256 + tid;
    int r = gidx >> 3, g = gidx & 7;
    int gs = g ^ (r & 7);
    ag[i] = (size_t)(bm * 128 + r) * KB + gs * 16;
    bg[i] = (size_t)(bn * 128 + r) * KB + gs * 16;
  }
  int aoff[2][4], boff[2][4];
#pragma unroll
  for (int ks = 0; ks < 2; ++ks) {
#pragma unroll
    for (int t = 0; t < 4; ++t) {
      int ra = wm * 64 + t * 16 + lc;
      aoff[ks][t] = ra * 128 + (((ks * 4 + kq) ^ (ra & 7)) << 4);
      int rb = wn * 64 + t * 16 + lc;
      boff[ks][t] = 16384 + rb * 128 + (((ks * 4 + kq) ^ (rb & 7)) << 4);
    }
  }
#pragma unroll
  for (int ti = 0; ti < 4; ++ti)
#pragma unroll
    for (int tj = 0; tj < 4; ++tj) {
      intx4 z = {0, 0, 0, 0};
      acc[ti][tj] = z;
    }

  for (int kt = 0; kt < KB / 128; ++kt) {
    __syncthreads();
    const int k0 = kt * 128;
#pragma unroll
    for (int i = 0; i < 4; ++i) {
      async16(A + ag[i] + k0, lds + i * 4096 + wave * 1024);
      async16(B + bg[i] + k0, lds + 16384 + i * 4096 + wave * 1024);
    }
    asm volatile("s_waitcnt vmcnt(0)" ::: "memory");
    __syncthreads();
#pragma unroll
    for (int ks = 0; ks < 2; ++ks) {
      intx4 af[4], bfr[4];
#pragma unroll
      for (int t = 0; t < 4; ++t) af[t] = *(const intx4*)(lds + aoff[ks][t]);
#pragma unroll
      for (int t = 0; t < 4; ++t) bfr[t] = *(const intx4*)(lds + boff[ks][t]);
#pragma unroll
      for (int ti = 0; ti < 4; ++ti)
#pragma unroll
        for (int tj = 0; tj < 4; ++tj)
          acc[ti][tj] =
              __builtin_amdgcn_mfma_i32_16x16x64_i8(af[ti], bfr[tj], acc[ti][tj], 0, 0, 0);
    }
  }
}

// ---------------- GEMM1 + dequant + exact GELU + fp32 h store + row |h| max ---------
__global__ __launch_bounds__(256) void k_gemm1(const signed char* __restrict__ A,
                                               const signed char* __restrict__ B,
                                               const float* __restrict__ dqx,
                                               const double* __restrict__ sums,
                                               float* __restrict__ H,
                                               float* __restrict__ rowmax) {
  __shared__ __attribute__((aligned(16))) char lds[32768];
  __shared__ float smax[128];
  const int tid = threadIdx.x;
  const int bm = blockIdx.x, bn = blockIdx.y;
  if (tid < 128) smax[tid] = 0.0f;

  intx4 acc[4][4];
  gemm_mainloop<1024>(A, B, bm, bn, tid, lds, acc);

  const int wave = tid >> 6, lane = tid & 63;
  const int wm = wave >> 1, wn = wave & 1;
  const int kq = lane >> 4, lc = lane & 15;
  const float s1 = fmaxf((float)(sums[0] * (1.0 / 4194304.0)), EPSQ);
#pragma unroll
  for (int ti = 0; ti < 4; ++ti) {
#pragma unroll
    for (int r = 0; r < 4; ++r) {
      const int lrow = wm * 64 + ti * 16 + kq * 4 + r;
      const int crow = bm * 128 + lrow;  // chunk-local row
      const float f = s1 * dqx[crow];
      float mx = 0.f;
#pragma unroll
      for (int tj = 0; tj < 4; ++tj) {
        const int gcol = bn * 128 + wn * 64 + tj * 16 + lc;
        float y = (float)acc[ti][tj][r] * f;
        float h = 0.5f * y * (1.0f + erff(y * 0.70710678118654752f));
        H[(size_t)crow * 4096 + gcol] = h;
        mx = fmaxf(mx, fabsf(h));
      }
      atomicMax((unsigned int*)&smax[lrow], __float_as_uint(mx));
    }
  }
  __syncthreads();
  if (tid < 128)
    atomicMax((unsigned int*)&rowmax[bm * 128 + tid], __float_as_uint(smax[tid]));
}

// ---------------- quantize h (fp32, chunk-local) -> int8 (scale from rowmax) --------
__global__ __launch_bounds__(256) void k_quanth(const float* __restrict__ H,
                                                const float* __restrict__ rowmax,
                                                signed char* __restrict__ HQ) {
  const size_t gid = (size_t)blockIdx.x * 256 + threadIdx.x;
  const size_t base = gid * 4;
  const int row = (int)(base >> 12);  // 4096 per row
  const float m = fmaxf(rowmax[row], EPSQ);
  const float scale = 127.f / m;
  float4 h = *(const float4*)(H + base);
  unsigned int p = ((unsigned int)(q8(h.x, scale, -128.f, 127.f) & 0xff)) |
                   ((unsigned int)(q8(h.y, scale, -128.f, 127.f) & 0xff) << 8) |
                   ((unsigned int)(q8(h.z, scale, -128.f, 127.f) & 0xff) << 16) |
                   ((unsigned int)(q8(h.w, scale, -128.f, 127.f) & 0xff) << 24);
  *(unsigned int*)(HQ + base) = p;
}

// ---------------- GEMM2 + dequant -> fp32 out (chunk-local) ----------------
__global__ __launch_bounds__(256) void k_gemm2(const signed char* __restrict__ A,
                                               const signed char* __restrict__ B,
                                               const float* __restrict__ rowmax,
                                               const double* __restrict__ sums,
                                               float* __restrict__ OUT) {
  __shared__ __attribute__((aligned(16))) char lds[32768];
  const int tid = threadIdx.x;
  const int bm = blockIdx.x, bn = blockIdx.y;

  intx4 acc[4][4];
  gemm_mainloop<4096>(A, B, bm, bn, tid, lds, acc);

  const int wave = tid >> 6, lane = tid & 63;
  const int wm = wave >> 1, wn = wave & 1;
  const int kq = lane >> 4, lc = lane & 15;
  const float s2 = fmaxf((float)(sums[0] * (1.0 / 4194304.0)), EPSQ);
#pragma unroll
  for (int ti = 0; ti < 4; ++ti) {
#pragma unroll
    for (int r = 0; r < 4; ++r) {
      const int crow = bm * 128 + wm * 64 + ti * 16 + kq * 4 + r;
      const float dqh = fmaxf(rowmax[crow], EPSQ) * (1.f / 127.f);
      const float f = s2 * dqh;
#pragma unroll
      for (int tj = 0; tj < 4; ++tj) {
        const int gcol = bn * 128 + wn * 64 + tj * 16 + lc;
        OUT[(size_t)crow * 1024 + gcol] = (float)acc[ti][tj][r] * f;
      }
    }
  }
}

// ---------------- launcher ----------------
extern "C" void kernel_launch(void* const* d_in, const int* in_sizes, int n_in,
                              void* d_out, int out_size, void* d_ws, size_t ws_size,
                              hipStream_t stream) {
  const float* X  = (const float*)d_in[0];  // [16384][1024] fp32
  const float* W1 = (const float*)d_in[1];  // [4096][1024]  fp32
  const float* W2 = (const float*)d_in[2];  // [1024][4096]  fp32
  float* OUT = (float*)d_out;               // [16384][1024] fp32 (64 MB)

  char* ws = (char*)d_ws;
  // Fixed-footprint region: 9 MB
  signed char* W1Q = (signed char*)(ws);                            // 4 MB
  signed char* W2Q = (signed char*)(ws + (4u << 20));               // 4 MB
  float* DQX       = (float*)(ws + (8u << 20));                     // 64 KB
  float* ROWMAX    = (float*)(ws + (8u << 20) + 65536);             // 64 KB
  double* SUMS     = (double*)(ws + (8u << 20) + 131072);           // 16 B
  const size_t fixed = 9u << 20;

  // XQ (16384x1024 i8 = 16 MB) aliases the TOP 16 MB of fp32 d_out (64 MB).
  // Chunk c's gemm1 reads XQ bytes 48MB+[c*R*1024,(c+1)*R*1024); OUT written so
  // far covers [0, c*R*4096). Overlap needs c*R*3072 > 48MB i.e. c*R > 16384 —
  // never. Last chunk's gemm2 clobbers its own XQ tail only after its gemm1 read
  // (stream order). OUT writes re-cover all 64 MB (poison-safe).
  signed char* XQ = (signed char*)((char*)d_out + 50331648ull);

  // Pick largest row-chunk R fitting ws_size: need fixed + R*4096*(4+1) bytes.
  int R = 128;
  const int cands[8] = {16384, 8192, 4096, 2048, 1024, 512, 256, 128};
  for (int i = 0; i < 8; ++i) {
    if (fixed + (size_t)cands[i] * 20480ull <= ws_size) { R = cands[i]; break; }
  }
  signed char* HQ = (signed char*)(ws + fixed);                     // R*4096 B
  float* H        = (float*)(ws + fixed + (size_t)R * 4096ull);     // R*16384 B

  hipLaunchKernelGGL(k_init, dim3(64), dim3(256), 0, stream, ROWMAX, SUMS);
  hipLaunchKernelGGL(k_absmean, dim3(2048), dim3(256), 0, stream, W1, SUMS + 0);
  hipLaunchKernelGGL(k_absmean, dim3(2048), dim3(256), 0, stream, W2, SUMS + 1);
  hipLaunchKernelGGL(k_quantw, dim3(2048), dim3(256), 0, stream, W1, W1Q, SUMS + 0);
  hipLaunchKernelGGL(k_quantw, dim3(2048), dim3(256), 0, stream, W2, W2Q, SUMS + 1);
  hipLaunchKernelGGL(k_quantx, dim3(16384), dim3(256), 0, stream, X, XQ, DQX);

  const int nchunk = 16384 / R;
  for (int c = 0; c < nchunk; ++c) {
    const int row0 = c * R;
    hipLaunchKernelGGL(k_gemm1, dim3(R / 128, 32), dim3(256), 0, stream,
                       XQ + (size_t)row0 * 1024, W1Q, DQX + row0, SUMS, H, ROWMAX + row0);
    hipLaunchKernelGGL(k_quanth, dim3(R * 4), dim3(256), 0, stream,
                       H, ROWMAX + row0, HQ);
    hipLaunchKernelGGL(k_gemm2, dim3(R / 128, 8), dim3(256), 0, stream,
                       HQ, W2Q, ROWMAX + row0, SUMS + 1, OUT + (size_t)row0 * 1024);
  }
}